// Round 20
// baseline (126.937 us; speedup 1.0000x reference)
//
#include <hip/hip_runtime.h>
#include <cstdint>
#include <cstddef>

typedef __bf16 bf16_t;
typedef uint32_t u32;
typedef __bf16 bf16x4 __attribute__((ext_vector_type(4)));
typedef __bf16 bf16x8 __attribute__((ext_vector_type(8)));
typedef float f32x4 __attribute__((ext_vector_type(4)));
typedef float f32x16 __attribute__((ext_vector_type(16)));

__device__ __forceinline__ void gload_lds16(const bf16_t* g, bf16_t* l) {
  __builtin_amdgcn_global_load_lds((const __attribute__((address_space(1))) void*)g,
                                   (__attribute__((address_space(3))) void*)l,
                                   16, 0, 0);
}

__device__ __forceinline__ f32x4 mfma16(bf16x8 a, bf16x8 b, f32x4 c) {
  return __builtin_amdgcn_mfma_f32_16x16x32_bf16(a, b, c, 0, 0, 0);
}
__device__ __forceinline__ f32x16 mfma32(bf16x8 a, bf16x8 b, f32x16 c) {
  return __builtin_amdgcn_mfma_f32_32x32x16_bf16(a, b, c, 0, 0, 0);
}

#define LOG2E 1.4426950408889634f

// ---------------- fused prep (R17 verbatim) ----------------
__global__ __launch_bounds__(256)
void prep_all(const float* __restrict__ img0, const float* __restrict__ img1,
              const float* __restrict__ mask,
              const float* __restrict__ wp, const float* __restrict__ wkv,
              const float* __restrict__ wqv, const float* __restrict__ wfc1,
              const float* __restrict__ wfc2,
              bf16_t* __restrict__ xp0, bf16_t* __restrict__ xp1,
              float* __restrict__ pe, float* __restrict__ bias,
              bf16_t* __restrict__ wpT, bf16_t* __restrict__ wkvT,
              bf16_t* __restrict__ wqT, bf16_t* __restrict__ wfc1T,
              bf16_t* __restrict__ wfc2T) {
  __shared__ float tl[64 * 65];
  int bid = blockIdx.x, tid = threadIdx.x;
  if (bid < 1536) {
    int imgsel = bid >= 768;
    int t = (bid - (imgsel ? 768 : 0)) * 256 + tid;
    const float* img = imgsel ? img1 : img0;
    bf16_t* xp = imgsel ? xp1 : xp0;
    int wpp = t & 31, p1 = (t >> 5) & 7, hp = (t >> 8) & 31, rest = t >> 13;
    int b = rest / 3, c = rest - b * 3;
    const float* src = img + (((size_t)(b * 3 + c) * 256 + hp * 8 + p1) * 256 + wpp * 8);
    float4 v0 = *(const float4*)src;
    float4 v1 = *(const float4*)(src + 4);
    int row = b * 1024 + hp * 32 + wpp;
    bf16_t* dst = xp + (size_t)row * 192 + p1 * 24 + c;
    dst[0]  = (bf16_t)v0.x; dst[3]  = (bf16_t)v0.y; dst[6]  = (bf16_t)v0.z; dst[9]  = (bf16_t)v0.w;
    dst[12] = (bf16_t)v1.x; dst[15] = (bf16_t)v1.y; dst[18] = (bf16_t)v1.z; dst[21] = (bf16_t)v1.w;
  } else if (bid < 2560) {
    int t = bid - 1536, c = tid;
    int i2 = c & ~1;
    float div = __expf((float)i2 * (-9.210340371976184f / 256.0f));
    float arg = (float)t * div;
    float sv, cv;
    __sincosf(arg, &sv, &cv);
    pe[t * 256 + c] = (c & 1) ? cv : sv;
  } else if (bid < 2592) {
    int g = (bid - 2560) * 256 + tid;   // 8192
    int b = g >> 10, t = g & 1023, hp = t >> 5, wpp = t & 31;
    const float* mp = mask + ((size_t)b * 256 + hp * 8) * 256 + wpp * 8;
    float s = 0.f;
    #pragma unroll
    for (int p1 = 0; p1 < 8; p1++) {
      float4 a = *(const float4*)(mp + p1 * 256);
      float4 c2 = *(const float4*)(mp + p1 * 256 + 4);
      s += a.x + a.y + a.z + a.w + c2.x + c2.y + c2.z + c2.w;
    }
    bias[g] = (s > 0.f) ? 0.f : (-100.f * LOG2E);   // log2-domain bias
  } else {
    int i = bid - 2592;
    const float* src; bf16_t* dst; int srcN, dstK, NT;
    if (i >= 172) {                  // zero-pad wfc2T rows 192..255
      int j = i - 172;
      bf16_t* p = wfc2T + 192 * 1024 + j * 8192 + tid * 32;
      bf16x8 z;
      #pragma unroll
      for (int e = 0; e < 8; e++) z[e] = (bf16_t)0.0f;
      *(bf16x8*)(p) = z; *(bf16x8*)(p + 8) = z;
      *(bf16x8*)(p + 16) = z; *(bf16x8*)(p + 24) = z;
      return;
    }
    if (i < 12)       { src = wp;   dst = wpT;   srcN = 256;  dstK = 192;  NT = 4; }
    else if (i < 44)  { i -= 12;  src = wkv;  dst = wkvT;  srcN = 512;  dstK = 256;  NT = 8; }
    else if (i < 60)  { i -= 44;  src = wqv;  dst = wqT;   srcN = 512;  dstK = 256;  NT = 4; }
    else if (i < 124) { i -= 60;  src = wfc1; dst = wfc1T; srcN = 1024; dstK = 256;  NT = 16; }
    else              { i -= 124; src = wfc2; dst = wfc2T; srcN = 192;  dstK = 1024; NT = 3; }
    int kt = i / NT, nt = i - kt * NT;
    #pragma unroll
    for (int j = 0; j < 4; j++) {
      int r = (tid >> 4) + 16 * j, c = (tid & 15) * 4;
      float4 v = *(const float4*)(src + (size_t)(kt * 64 + r) * srcN + nt * 64 + c);
      tl[r * 65 + c] = v.x; tl[r * 65 + c + 1] = v.y;
      tl[r * 65 + c + 2] = v.z; tl[r * 65 + c + 3] = v.w;
    }
    __syncthreads();
    #pragma unroll
    for (int j = 0; j < 16; j++) {
      int flat = tid + 256 * j;
      int n_l = flat >> 6, k_l = flat & 63;
      dst[(size_t)(nt * 64 + n_l) * dstK + kt * 64 + k_l] = (bf16_t)tl[k_l * 65 + n_l];
    }
  }
}

// bijective XCD-chunked remap of the (x,y) plane; requires nwg % 8 == 0
__device__ __forceinline__ void xcd_swizzle(int& bx, int& by) {
  int nx = gridDim.x, ny = gridDim.y;
  int nwg = nx * ny;
  int flat = blockIdx.y * nx + blockIdx.x;
  int q8 = nwg >> 3;
  int swz = (flat & 7) * q8 + (flat >> 3);
  bx = swz % nx;
  by = swz / nx;
}

// ---------------- GEMM 128-tile (R17 body + T1 XCD swizzle) ----------------
template<int EPI, int BN>
__global__ __launch_bounds__(256, 3)
void gemm128d(const bf16_t* __restrict__ A_, const bf16_t* __restrict__ A2,
              const bf16_t* __restrict__ Bt_, const bf16_t* __restrict__ Bt2,
              int M, int N, int K,
              const float* __restrict__ bias_, const float* __restrict__ bias2,
              const float* __restrict__ pe,
              bf16_t* __restrict__ out_b, bf16_t* __restrict__ out_b2,
              bf16_t* __restrict__ out_b3) {
  constexpr int NF = BN / 32;
  __shared__ bf16_t alds[4 * 128 * 8];
  __shared__ bf16_t blds[4 * BN * 8];
  const int tid = threadIdx.x;
  const int lane = tid & 63, wid = tid >> 6;
  const int ln15 = lane & 15, hi = lane >> 4;
  int bx, by;
  xcd_swizzle(bx, by);
  const int brow = bx * 128;
  int bcol = by * BN;
  const bf16_t* A = A_;
  const bf16_t* Bt = Bt_;
  const float* bias = bias_;
  bool qpart = false;
  if (EPI == 0 && blockIdx.z) A = A2;
  if (EPI == 5 && by >= 4) {
    qpart = true; A = A2; Bt = Bt2; bias = bias2; bcol -= 512;
  }
  const int wr = wid >> 1, wc = wid & 1;

  f32x4 acc[4][NF];
  #pragma unroll
  for (int m = 0; m < 4; m++)
    #pragma unroll
    for (int n = 0; n < NF; n++) acc[m][n] = (f32x4){0.f, 0.f, 0.f, 0.f};

  for (int k0 = 0; k0 < K; k0 += 32) {
    #pragma unroll
    for (int s = 0; s < 2; s++) {              // A: 512 chunks [kb4][row128]
      int c = tid + s * 256; int kb = c >> 7, row = c & 127;
      gload_lds16(A + (size_t)(brow + row) * K + k0 + kb * 8,
                  &alds[(size_t)(s * 256 + wid * 64) * 8]);
    }
    #pragma unroll
    for (int s = 0; s < BN / 64; s++) {        // B: BN*4 chunks [kb4][rowBN]
      int c = tid + s * 256; int kb = c / BN, row = c % BN;
      gload_lds16(Bt + (size_t)(bcol + row) * K + k0 + kb * 8,
                  &blds[(size_t)(s * 256 + wid * 64) * 8]);
    }
    __syncthreads();
    bf16x8 bfr[NF];
    #pragma unroll
    for (int n = 0; n < NF; n++)
      bfr[n] = *(const bf16x8*)&blds[(size_t)(hi * BN + wc * (BN / 2) + n * 16 + ln15) * 8];
    #pragma unroll
    for (int m = 0; m < 4; m++) {
      bf16x8 af = *(const bf16x8*)&alds[(size_t)(hi * 128 + wr * 64 + m * 16 + ln15) * 8];
      #pragma unroll
      for (int n = 0; n < NF; n++)
        acc[m][n] = mfma16(af, bfr[n], acc[m][n]);
    }
    __syncthreads();
  }

  #pragma unroll
  for (int m = 0; m < 4; m++) {
    #pragma unroll
    for (int n = 0; n < NF; n++) {
      #pragma unroll
      for (int r = 0; r < 4; r++) {
        int grow = brow + wr * 64 + m * 16 + hi * 4 + r;
        int gcol = bcol + wc * (BN / 2) + n * 16 + ln15;
        float v = acc[m][n][r];
        if (EPI == 0) {
          v += bias[gcol] + pe[(grow & 1023) * 256 + gcol];
          bf16_t* outx = blockIdx.z ? out_b2 : out_b;
          outx[(size_t)grow * N + gcol] = (bf16_t)v;
        } else if (EPI == 5) {
          v += bias[gcol];
          int b = grow >> 10, t = grow & 1023;
          if (!qpart) {
            if (gcol < 256) {
              int h = gcol >> 5, d = gcol & 31;
              out_b[(((size_t)(b * 8 + h) * 1024 + t) << 5) + d] = (bf16_t)v;
            } else {
              int c2 = gcol - 256; int h = c2 >> 5, d = c2 & 31;
              out_b2[(((size_t)(b * 8 + h) * 32 + d) << 10) + t] = (bf16_t)v;
            }
          } else {
            v *= (0.17677669529663687f * LOG2E);   // 1/sqrt(32) * log2(e)
            int h = gcol >> 5, d = gcol & 31;
            out_b3[(((size_t)(b * 8 + h) * 1024 + t) << 5) + d] = (bf16_t)v;
          }
        } else if (EPI == 3) {
          v += bias[gcol];
          float gg = 0.5f * v * (1.0f + erff(v * 0.7071067811865476f));
          out_b[(size_t)grow * N + gcol] = (bf16_t)gg;
        }
      }
    }
  }
}

// ---------------- fc2 GEMM (R17 body + T1 XCD swizzle) ----------------
template<int BN>
__global__ __launch_bounds__(256)
void gemm_fc2(const bf16_t* __restrict__ A, const bf16_t* __restrict__ Bt,
              int M, int N, int K, const float* __restrict__ bias,
              float* __restrict__ out_f) {
  constexpr int NF = BN / 32;
  __shared__ bf16_t alds[2][8 * 64 * 8];
  __shared__ bf16_t blds[2][8 * BN * 8];
  const int tid = threadIdx.x;
  const int lane = tid & 63, wid = tid >> 6;
  const int ln15 = lane & 15, hi = lane >> 4;
  int bx, by;
  xcd_swizzle(bx, by);
  const int brow = bx * 64;
  const int bcol = by * BN;
  const int wr = wid >> 1, wc = wid & 1;

  auto stage = [&](int buf, int k0) {
    #pragma unroll
    for (int s = 0; s < 2; s++) {
      int c = tid + s * 256; int kb = c >> 6, row = c & 63;
      gload_lds16(A + (size_t)(brow + row) * K + k0 + kb * 8,
                  &alds[buf][(size_t)(s * 256 + wid * 64) * 8]);
    }
    #pragma unroll
    for (int s = 0; s < BN / 32; s++) {
      int c = tid + s * 256; int kb = c / BN, row = c & (BN - 1);
      gload_lds16(Bt + (size_t)(bcol + row) * K + k0 + kb * 8,
                  &blds[buf][(size_t)(s * 256 + wid * 64) * 8]);
    }
  };

  f32x4 acc[2][NF];
  #pragma unroll
  for (int m = 0; m < 2; m++)
    #pragma unroll
    for (int n = 0; n < NF; n++) acc[m][n] = (f32x4){0.f, 0.f, 0.f, 0.f};

  stage(0, 0);
  __syncthreads();
  int cur = 0;
  const int NT = K >> 6;
  for (int t = 0; t < NT; t++) {
    if (t + 1 < NT) stage(cur ^ 1, (t + 1) << 6);
    bf16x8 af[2][2], bfr[2][NF];
    #pragma unroll
    for (int kk = 0; kk < 2; kk++) {
      #pragma unroll
      for (int m = 0; m < 2; m++)
        af[kk][m] = *(const bf16x8*)&alds[cur][(size_t)((kk * 4 + hi) * 64 + wr * 32 + m * 16 + ln15) * 8];
      #pragma unroll
      for (int n = 0; n < NF; n++)
        bfr[kk][n] = *(const bf16x8*)&blds[cur][(size_t)((kk * 4 + hi) * BN + wc * (BN / 2) + n * 16 + ln15) * 8];
    }
    #pragma unroll
    for (int kk = 0; kk < 2; kk++)
      #pragma unroll
      for (int m = 0; m < 2; m++)
        #pragma unroll
        for (int n = 0; n < NF; n++)
          acc[m][n] = mfma16(af[kk][m], bfr[kk][n], acc[m][n]);
    __syncthreads();
    cur ^= 1;
  }

  #pragma unroll
  for (int m = 0; m < 2; m++) {
    #pragma unroll
    for (int n = 0; n < NF; n++) {
      #pragma unroll
      for (int r = 0; r < 4; r++) {
        int grow = brow + wr * 32 + m * 16 + hi * 4 + r;
        int gcol = bcol + wc * (BN / 2) + n * 16 + ln15;
        float v = acc[m][n][r] + bias[gcol];
        int b = grow >> 10, t = grow & 1023;
        int hp = t >> 5, wpp = t & 31;
        int p = gcol / 3; int c = gcol - p * 3;
        int p1 = p >> 3, p2 = p & 7;
        out_f[(((size_t)(b * 3 + c) * 256 + hp * 8 + p1) * 256) + wpp * 8 + p2] = v;
      }
    }
  }
}

// ---------------- attention (R11 verbatim): in-block split-K flash ----------------
union PW { u32 w[4]; bf16x8 v; };

__device__ __forceinline__ u32 pkbf(float a, float b) {
  union { bf16_t h[2]; u32 w; } u;
  u.h[0] = (bf16_t)a; u.h[1] = (bf16_t)b;
  return u.w;
}

__device__ __forceinline__ void pl32swap(u32& a, u32& b) {
  asm volatile("v_permlane32_swap_b32 %0, %1" : "+v"(a), "+v"(b));
}

#define SMEM_BYTES 32768

__device__ __forceinline__ void stage_kv(const bf16_t* kbase, const bf16_t* vbase,
                                         int ch, char* smem, int cur,
                                         int tid, int wid) {
  bf16_t* kl = (bf16_t*)(smem + cur * 8192);
  bf16_t* vl = (bf16_t*)(smem + 16384 + cur * 8192);
  #pragma unroll
  for (int s = 0; s < 2; s++) {
    int c = tid + s * 256;
    int row = c >> 2, cs = (c & 3) ^ (row & 3);
    gload_lds16(kbase + (size_t)(ch * 128 + row) * 32 + cs * 8,
                kl + (size_t)(s * 256 + wid * 64) * 8);
  }
  #pragma unroll
  for (int s = 0; s < 2; s++) {
    int c = tid + s * 256;
    int row = c >> 4, cs = (c & 15) ^ (row & 15);
    gload_lds16(vbase + (size_t)row * 1024 + ch * 128 + cs * 8,
                vl + (size_t)(s * 256 + wid * 64) * 8);
  }
}

__global__ __launch_bounds__(256, 4)
void attn_kernel(const bf16_t* __restrict__ q, const bf16_t* __restrict__ k,
                 const bf16_t* __restrict__ vt, const float* __restrict__ bias,
                 bf16_t* __restrict__ out) {
  __shared__ __align__(16) char smem[SMEM_BYTES];

  int tid = threadIdx.x, lane = tid & 63, wid = tid >> 6;
  int l31 = lane & 31, g = lane >> 5;
  int x = blockIdx.x & 7, idx = blockIdx.x >> 3;
  int qt = idx & 31;
  int bh = ((idx >> 5) << 3) | x;
  int b = bh >> 3, h = bh & 7;
  int q0 = qt * 32;
  const bf16_t* qp = q + ((size_t)bh * 1024 + q0 + l31) * 32;
  bf16x8 qf0 = *(const bf16x8*)(qp + g * 8);
  bf16x8 qf1 = *(const bf16x8*)(qp + 16 + g * 8);
  const bf16_t* kbase = k + (size_t)bh * 32768;
  const bf16_t* vbase = vt + (size_t)bh * 32768;
  const float* bb = bias + b * 1024;

  f32x16 acc;
  #pragma unroll
  for (int r = 0; r < 16; r++) acc[r] = 0.f;
  float lsum = 0.f;

  stage_kv(kbase, vbase, 0, smem, 0, tid, wid);
  __syncthreads();

  int cur = 0;
  for (int ch = 0; ch < 8; ch++) {
    if (ch < 7) stage_kv(kbase, vbase, ch + 1, smem, cur ^ 1, tid, wid);
    const bf16_t* kl = (const bf16_t*)(smem + cur * 8192);
    const bf16_t* vl = (const bf16_t*)(smem + 16384 + cur * 8192);
    int base = ch * 128 + wid * 32;
    int row0 = wid * 32 + l31;
    bf16x8 kA = *(const bf16x8*)(kl + (size_t)(row0 * 4 + (g ^ (row0 & 3))) * 8);
    bf16x8 kB = *(const bf16x8*)(kl + (size_t)(row0 * 4 + ((2 + g) ^ (row0 & 3))) * 8);
    bf16x8 vA = *(const bf16x8*)(vl + (size_t)(l31 * 16 + ((wid * 4 + g) ^ (l31 & 15))) * 8);
    bf16x8 vB = *(const bf16x8*)(vl + (size_t)(l31 * 16 + ((wid * 4 + 2 + g) ^ (l31 & 15))) * 8);
    f32x4 c0 = *(const f32x4*)(bb + base + 4 * g);
    f32x4 c1 = *(const f32x4*)(bb + base + 8 + 4 * g);
    f32x4 c2 = *(const f32x4*)(bb + base + 16 + 4 * g);
    f32x4 c3 = *(const f32x4*)(bb + base + 24 + 4 * g);
    f32x16 S;
    S[0] = c0[0]; S[1] = c0[1]; S[2] = c0[2]; S[3] = c0[3];
    S[4] = c1[0]; S[5] = c1[1]; S[6] = c1[2]; S[7] = c1[3];
    S[8] = c2[0]; S[9] = c2[1]; S[10] = c2[2]; S[11] = c2[3];
    S[12] = c3[0]; S[13] = c3[1]; S[14] = c3[2]; S[15] = c3[3];
    S = mfma32(kA, qf0, S);
    S = mfma32(kB, qf1, S);
    float p[16];
    #pragma unroll
    for (int r = 0; r < 16; r++) p[r] = exp2f(S[r]);
    lsum += (((p[0] + p[1]) + (p[2] + p[3])) + ((p[4] + p[5]) + (p[6] + p[7]))) +
            (((p[8] + p[9]) + (p[10] + p[11])) + ((p[12] + p[13]) + (p[14] + p[15])));
    u32 w[8];
    #pragma unroll
    for (int j = 0; j < 8; j++) w[j] = pkbf(p[2 * j], p[2 * j + 1]);
    u32 xa = w[2], ya = w[0]; pl32swap(xa, ya);
    u32 xb = w[3], yb = w[1]; pl32swap(xb, yb);
    u32 xc = w[6], yc = w[4]; pl32swap(xc, yc);
    u32 xd = w[7], yd = w[5]; pl32swap(xd, yd);
    PW A0, A1;
    A0.w[0] = g ? xa : w[0];  A0.w[2] = g ? w[2] : ya;
    A0.w[1] = g ? xb : w[1];  A0.w[3] = g ? w[3] : yb;
    A1.w[0] = g ? xc : w[4];  A1.w[2] = g ? w[6] : yc;
    A1.w[1] = g ? xd : w[5];  A1.w[3] = g ? w[7] : yd;
    acc = mfma32(A0.v, vA, acc);
    acc = mfma32(A1.v, vB, acc);
    __syncthreads();
    cur ^= 1;
  }

  float* OL = (float*)smem;
  float* LS = (float*)(smem + 16896);
  #pragma unroll
  for (int r = 0; r < 16; r++) {
    int row = (r & 3) + 8 * (r >> 2) + 4 * g;
    OL[wid * 1056 + row * 33 + l31] = acc[r];
  }
  lsum += __shfl_xor(lsum, 32);
  LS[wid * 32 + l31] = lsum;
  __syncthreads();

  int qq = tid >> 3, d0 = (tid & 7) * 4;
  float l = LS[qq] + LS[32 + qq] + LS[64 + qq] + LS[96 + qq];
  float o0 = 0.f, o1 = 0.f, o2 = 0.f, o3 = 0.f;
  #pragma unroll
  for (int w2 = 0; w2 < 4; w2++) {
    const float* p = &OL[w2 * 1056 + qq * 33 + d0];
    o0 += p[0]; o1 += p[1]; o2 += p[2]; o3 += p[3];
  }
  float linv = 1.f / l;
  bf16x4 ov;
  ov[0] = (bf16_t)(o0 * linv); ov[1] = (bf16_t)(o1 * linv);
  ov[2] = (bf16_t)(o2 * linv); ov[3] = (bf16_t)(o3 * linv);
  *(bf16x4*)(out + ((size_t)b * 1024 + q0 + qq) * 256 + h * 32 + d0) = ov;
}

// ---------------- launch ----------------
extern "C" void kernel_launch(void* const* d_in, const int* in_sizes, int n_in,
                              void* d_out, int out_size, void* d_ws, size_t ws_size,
                              hipStream_t stream) {
  (void)in_sizes; (void)n_in; (void)out_size; (void)ws_size;
  const float* img0    = (const float*)d_in[0];
  const float* img1    = (const float*)d_in[1];
  const float* mask    = (const float*)d_in[2];
  const float* w_patch = (const float*)d_in[3];
  const float* b_patch = (const float*)d_in[4];
  const float* w_kv    = (const float*)d_in[5];
  const float* b_kv    = (const float*)d_in[6];
  const float* w_qv    = (const float*)d_in[7];
  const float* b_qv    = (const float*)d_in[8];
  const float* w_fc1   = (const float*)d_in[9];
  const float* b_fc1   = (const float*)d_in[10];
  const float* w_fc2   = (const float*)d_in[11];
  const float* b_fc2   = (const float*)d_in[12];
  float* out = (float*)d_out;

  char* ws = (char*)d_ws;
  float*  pe    = (float*)(ws + 0);
  float*  bias  = (float*)(ws + 1048576);
  bf16_t* wpT   = (bf16_t*)(ws + 1081344);
  bf16_t* wkvT  = (bf16_t*)(ws + 1179648);
  bf16_t* wqT   = (bf16_t*)(ws + 1441792);
  bf16_t* wfc1T = (bf16_t*)(ws + 1572864);
  bf16_t* wfc2T = (bf16_t*)(ws + 2097152);
  bf16_t* xp0   = (bf16_t*)(ws + 2621440);
  bf16_t* xp1   = (bf16_t*)(ws + 5767168);
  bf16_t* x0    = (bf16_t*)(ws + 8912896);
  bf16_t* x1    = (bf16_t*)(ws + 13107200);
  bf16_t* kbuf  = (bf16_t*)(ws + 17301504);
  bf16_t* vtbuf = (bf16_t*)(ws + 21495808);
  bf16_t* qbuf  = (bf16_t*)(ws + 25690112);
  bf16_t* aout  = (bf16_t*)(ws + 29884416);
  bf16_t* hbuf  = (bf16_t*)(ws + 34078720);

  prep_all<<<2772, 256, 0, stream>>>(img0, img1, mask, w_patch, w_kv, w_qv, w_fc1, w_fc2,
                                     xp0, xp1, pe, bias, wpT, wkvT, wqT, wfc1T, wfc2T);

  gemm128d<0, 64><<<dim3(64, 4, 2), 256, 0, stream>>>(xp0, xp1, wpT, nullptr, 8192, 256, 192,
                                                      b_patch, nullptr, pe, x0, x1, nullptr);
  gemm128d<5, 128><<<dim3(64, 6), 256, 0, stream>>>(x0, x1, wkvT, wqT, 8192, 512, 256,
                                                    b_kv, b_qv, nullptr, kbuf, vtbuf, qbuf);

  attn_kernel<<<2048, 256, 0, stream>>>(qbuf, kbuf, vtbuf, bias, aout);

  gemm128d<3, 128><<<dim3(64, 8), 256, 0, stream>>>(aout, nullptr, wfc1T, nullptr, 8192, 1024, 256,
                                                    b_fc1, nullptr, nullptr, hbuf, nullptr, nullptr);
  gemm_fc2<64><<<dim3(128, 3), 256, 0, stream>>>(hbuf, wfc2T, 8192, 256, 1024, b_fc2, out);
}

// Round 22
// 116.523 us; speedup vs baseline: 1.0894x; 1.0894x over previous
//
#include <hip/hip_runtime.h>
#include <cstdint>
#include <cstddef>

typedef __bf16 bf16_t;
typedef uint32_t u32;
typedef __bf16 bf16x4 __attribute__((ext_vector_type(4)));
typedef __bf16 bf16x8 __attribute__((ext_vector_type(8)));
typedef float f32x4 __attribute__((ext_vector_type(4)));
typedef float f32x16 __attribute__((ext_vector_type(16)));

__device__ __forceinline__ void gload_lds16(const bf16_t* g, bf16_t* l) {
  __builtin_amdgcn_global_load_lds((const __attribute__((address_space(1))) void*)g,
                                   (__attribute__((address_space(3))) void*)l,
                                   16, 0, 0);
}

__device__ __forceinline__ f32x4 mfma16(bf16x8 a, bf16x8 b, f32x4 c) {
  return __builtin_amdgcn_mfma_f32_16x16x32_bf16(a, b, c, 0, 0, 0);
}
__device__ __forceinline__ f32x16 mfma32(bf16x8 a, bf16x8 b, f32x16 c) {
  return __builtin_amdgcn_mfma_f32_32x32x16_bf16(a, b, c, 0, 0, 0);
}

#define LOG2E 1.4426950408889634f

// ---------------- fused prep ----------------
__global__ __launch_bounds__(256)
void prep_all(const float* __restrict__ img0, const float* __restrict__ img1,
              const float* __restrict__ mask,
              const float* __restrict__ wp, const float* __restrict__ wkv,
              const float* __restrict__ wqv, const float* __restrict__ wfc1,
              const float* __restrict__ wfc2,
              bf16_t* __restrict__ xp0, bf16_t* __restrict__ xp1,
              float* __restrict__ pe, float* __restrict__ bias,
              bf16_t* __restrict__ wpT, bf16_t* __restrict__ wkvT,
              bf16_t* __restrict__ wqT, bf16_t* __restrict__ wfc1T,
              bf16_t* __restrict__ wfc2T) {
  __shared__ float tl[64 * 65];
  int bid = blockIdx.x, tid = threadIdx.x;
  if (bid < 1536) {
    int imgsel = bid >= 768;
    int t = (bid - (imgsel ? 768 : 0)) * 256 + tid;
    const float* img = imgsel ? img1 : img0;
    bf16_t* xp = imgsel ? xp1 : xp0;
    int wpp = t & 31, p1 = (t >> 5) & 7, hp = (t >> 8) & 31, rest = t >> 13;
    int b = rest / 3, c = rest - b * 3;
    const float* src = img + (((size_t)(b * 3 + c) * 256 + hp * 8 + p1) * 256 + wpp * 8);
    float4 v0 = *(const float4*)src;
    float4 v1 = *(const float4*)(src + 4);
    int row = b * 1024 + hp * 32 + wpp;
    bf16_t* dst = xp + (size_t)row * 192 + p1 * 24 + c;
    dst[0]  = (bf16_t)v0.x; dst[3]  = (bf16_t)v0.y; dst[6]  = (bf16_t)v0.z; dst[9]  = (bf16_t)v0.w;
    dst[12] = (bf16_t)v1.x; dst[15] = (bf16_t)v1.y; dst[18] = (bf16_t)v1.z; dst[21] = (bf16_t)v1.w;
  } else if (bid < 2560) {
    int t = bid - 1536, c = tid;
    int i2 = c & ~1;
    float div = __expf((float)i2 * (-9.210340371976184f / 256.0f));
    float arg = (float)t * div;
    float sv, cv;
    __sincosf(arg, &sv, &cv);
    pe[t * 256 + c] = (c & 1) ? cv : sv;
  } else if (bid < 2592) {
    int g = (bid - 2560) * 256 + tid;   // 8192
    int b = g >> 10, t = g & 1023, hp = t >> 5, wpp = t & 31;
    const float* mp = mask + ((size_t)b * 256 + hp * 8) * 256 + wpp * 8;
    float s = 0.f;
    #pragma unroll
    for (int p1 = 0; p1 < 8; p1++) {
      float4 a = *(const float4*)(mp + p1 * 256);
      float4 c2 = *(const float4*)(mp + p1 * 256 + 4);
      s += a.x + a.y + a.z + a.w + c2.x + c2.y + c2.z + c2.w;
    }
    bias[g] = (s > 0.f) ? 0.f : (-100.f * LOG2E);   // log2-domain bias
  } else {
    int i = bid - 2592;
    const float* src; bf16_t* dst; int srcN, dstK, NT;
    if (i >= 172) {                  // zero-pad wfc2T rows 192..255
      int j = i - 172;
      bf16_t* p = wfc2T + 192 * 1024 + j * 8192 + tid * 32;
      bf16x8 z;
      #pragma unroll
      for (int e = 0; e < 8; e++) z[e] = (bf16_t)0.0f;
      *(bf16x8*)(p) = z; *(bf16x8*)(p + 8) = z;
      *(bf16x8*)(p + 16) = z; *(bf16x8*)(p + 24) = z;
      return;
    }
    if (i < 12)       { src = wp;   dst = wpT;   srcN = 256;  dstK = 192;  NT = 4; }
    else if (i < 44)  { i -= 12;  src = wkv;  dst = wkvT;  srcN = 512;  dstK = 256;  NT = 8; }
    else if (i < 60)  { i -= 44;  src = wqv;  dst = wqT;   srcN = 512;  dstK = 256;  NT = 4; }
    else if (i < 124) { i -= 60;  src = wfc1; dst = wfc1T; srcN = 1024; dstK = 256;  NT = 16; }
    else              { i -= 124; src = wfc2; dst = wfc2T; srcN = 192;  dstK = 1024; NT = 3; }
    int kt = i / NT, nt = i - kt * NT;
    #pragma unroll
    for (int j = 0; j < 4; j++) {
      int r = (tid >> 4) + 16 * j, c = (tid & 15) * 4;
      float4 v = *(const float4*)(src + (size_t)(kt * 64 + r) * srcN + nt * 64 + c);
      tl[r * 65 + c] = v.x; tl[r * 65 + c + 1] = v.y;
      tl[r * 65 + c + 2] = v.z; tl[r * 65 + c + 3] = v.w;
    }
    __syncthreads();
    #pragma unroll
    for (int j = 0; j < 16; j++) {
      int flat = tid + 256 * j;
      int n_l = flat >> 6, k_l = flat & 63;
      dst[(size_t)(nt * 64 + n_l) * dstK + kt * 64 + k_l] = (bf16_t)tl[k_l * 65 + n_l];
    }
  }
}

// ---------------- GEMM 128-tile, register-dieted, 3 blocks/CU target ----------------
template<int EPI, int BN>
__global__ __launch_bounds__(256, 3)
void gemm128d(const bf16_t* __restrict__ A_, const bf16_t* __restrict__ A2,
              const bf16_t* __restrict__ Bt_, const bf16_t* __restrict__ Bt2,
              int M, int N, int K,
              const float* __restrict__ bias_, const float* __restrict__ bias2,
              const float* __restrict__ pe,
              bf16_t* __restrict__ out_b, bf16_t* __restrict__ out_b2,
              bf16_t* __restrict__ out_b3, float* __restrict__ out_f) {
  constexpr int NF = BN / 32;                // 16-wide col frags per wave
  __shared__ bf16_t alds[4 * 128 * 8];       // [kb][row][8]  8 KB
  __shared__ bf16_t blds[4 * BN * 8];
  const int tid = threadIdx.x;
  const int lane = tid & 63, wid = tid >> 6;
  const int ln15 = lane & 15, hi = lane >> 4;
  const int brow = blockIdx.x * 128;
  int bcol = blockIdx.y * BN;
  const bf16_t* A = A_;
  const bf16_t* Bt = Bt_;
  const float* bias = bias_;
  bool qpart = false;
  if (EPI == 0 && blockIdx.z) A = A2;
  if (EPI == 5 && blockIdx.y >= 4) {
    qpart = true; A = A2; Bt = Bt2; bias = bias2; bcol -= 512;
  }
  const int wr = wid >> 1, wc = wid & 1;

  f32x4 acc[4][NF];
  #pragma unroll
  for (int m = 0; m < 4; m++)
    #pragma unroll
    for (int n = 0; n < NF; n++) acc[m][n] = (f32x4){0.f, 0.f, 0.f, 0.f};

  for (int k0 = 0; k0 < K; k0 += 32) {
    #pragma unroll
    for (int s = 0; s < 2; s++) {              // A: 512 chunks [kb4][row128]
      int c = tid + s * 256; int kb = c >> 7, row = c & 127;
      gload_lds16(A + (size_t)(brow + row) * K + k0 + kb * 8,
                  &alds[(size_t)(s * 256 + wid * 64) * 8]);
    }
    #pragma unroll
    for (int s = 0; s < BN / 64; s++) {        // B: BN*4 chunks [kb4][rowBN]
      int c = tid + s * 256; int kb = c / BN, row = c % BN;
      gload_lds16(Bt + (size_t)(bcol + row) * K + k0 + kb * 8,
                  &blds[(size_t)(s * 256 + wid * 64) * 8]);
    }
    __syncthreads();
    bf16x8 bfr[NF];
    #pragma unroll
    for (int n = 0; n < NF; n++)
      bfr[n] = *(const bf16x8*)&blds[(size_t)(hi * BN + wc * (BN / 2) + n * 16 + ln15) * 8];
    #pragma unroll
    for (int m = 0; m < 4; m++) {              // af loaded one-at-a-time: lower pressure
      bf16x8 af = *(const bf16x8*)&alds[(size_t)(hi * 128 + wr * 64 + m * 16 + ln15) * 8];
      #pragma unroll
      for (int n = 0; n < NF; n++)
        acc[m][n] = mfma16(af, bfr[n], acc[m][n]);
    }
    __syncthreads();
  }

  #pragma unroll
  for (int m = 0; m < 4; m++) {
    #pragma unroll
    for (int n = 0; n < NF; n++) {
      #pragma unroll
      for (int r = 0; r < 4; r++) {
        int grow = brow + wr * 64 + m * 16 + hi * 4 + r;
        int gcol = bcol + wc * (BN / 2) + n * 16 + ln15;
        float v = acc[m][n][r];
        if (EPI == 0) {
          v += bias[gcol] + pe[(grow & 1023) * 256 + gcol];
          bf16_t* outx = blockIdx.z ? out_b2 : out_b;
          outx[(size_t)grow * N + gcol] = (bf16_t)v;
        } else if (EPI == 5) {
          v += bias[gcol];
          int b = grow >> 10, t = grow & 1023;
          if (!qpart) {
            if (gcol < 256) {
              int h = gcol >> 5, d = gcol & 31;
              out_b[(((size_t)(b * 8 + h) * 1024 + t) << 5) + d] = (bf16_t)v;
            } else {
              int c2 = gcol - 256; int h = c2 >> 5, d = c2 & 31;
              out_b2[(((size_t)(b * 8 + h) * 32 + d) << 10) + t] = (bf16_t)v;
            }
          } else {
            v *= (0.17677669529663687f * LOG2E);   // 1/sqrt(32) * log2(e)
            int h = gcol >> 5, d = gcol & 31;
            out_b3[(((size_t)(b * 8 + h) * 1024 + t) << 5) + d] = (bf16_t)v;
          }
        } else if (EPI == 3) {
          v += bias[gcol];
          float gg = 0.5f * v * (1.0f + erff(v * 0.7071067811865476f));
          out_b[(size_t)grow * N + gcol] = (bf16_t)gg;
        }
      }
    }
  }
}

// ---------------- fc2 GEMM: BK=64, dbuf, BM=64 ----------------
template<int BN>
__global__ __launch_bounds__(256)
void gemm_fc2(const bf16_t* __restrict__ A, const bf16_t* __restrict__ Bt,
              int M, int N, int K, const float* __restrict__ bias,
              float* __restrict__ out_f) {
  constexpr int NF = BN / 32;
  __shared__ bf16_t alds[2][8 * 64 * 8];    // [buf][kb][row][8]
  __shared__ bf16_t blds[2][8 * BN * 8];
  const int tid = threadIdx.x;
  const int lane = tid & 63, wid = tid >> 6;
  const int ln15 = lane & 15, hi = lane >> 4;
  const int brow = blockIdx.x * 64;
  const int bcol = blockIdx.y * BN;
  const int wr = wid >> 1, wc = wid & 1;

  auto stage = [&](int buf, int k0) {
    #pragma unroll
    for (int s = 0; s < 2; s++) {
      int c = tid + s * 256; int kb = c >> 6, row = c & 63;
      gload_lds16(A + (size_t)(brow + row) * K + k0 + kb * 8,
                  &alds[buf][(size_t)(s * 256 + wid * 64) * 8]);
    }
    #pragma unroll
    for (int s = 0; s < BN / 32; s++) {
      int c = tid + s * 256; int kb = c / BN, row = c & (BN - 1);
      gload_lds16(Bt + (size_t)(bcol + row) * K + k0 + kb * 8,
                  &blds[buf][(size_t)(s * 256 + wid * 64) * 8]);
    }
  };

  f32x4 acc[2][NF];
  #pragma unroll
  for (int m = 0; m < 2; m++)
    #pragma unroll
    for (int n = 0; n < NF; n++) acc[m][n] = (f32x4){0.f, 0.f, 0.f, 0.f};

  stage(0, 0);
  __syncthreads();
  int cur = 0;
  const int NT = K >> 6;
  for (int t = 0; t < NT; t++) {
    if (t + 1 < NT) stage(cur ^ 1, (t + 1) << 6);
    bf16x8 af[2][2], bfr[2][NF];
    #pragma unroll
    for (int kk = 0; kk < 2; kk++) {
      #pragma unroll
      for (int m = 0; m < 2; m++)
        af[kk][m] = *(const bf16x8*)&alds[cur][(size_t)((kk * 4 + hi) * 64 + wr * 32 + m * 16 + ln15) * 8];
      #pragma unroll
      for (int n = 0; n < NF; n++)
        bfr[kk][n] = *(const bf16x8*)&blds[cur][(size_t)((kk * 4 + hi) * BN + wc * (BN / 2) + n * 16 + ln15) * 8];
    }
    #pragma unroll
    for (int kk = 0; kk < 2; kk++)
      #pragma unroll
      for (int m = 0; m < 2; m++)
        #pragma unroll
        for (int n = 0; n < NF; n++)
          acc[m][n] = mfma16(af[kk][m], bfr[kk][n], acc[m][n]);
    __syncthreads();
    cur ^= 1;
  }

  #pragma unroll
  for (int m = 0; m < 2; m++) {
    #pragma unroll
    for (int n = 0; n < NF; n++) {
      #pragma unroll
      for (int r = 0; r < 4; r++) {
        int grow = brow + wr * 32 + m * 16 + hi * 4 + r;
        int gcol = bcol + wc * (BN / 2) + n * 16 + ln15;
        float v = acc[m][n][r] + bias[gcol];
        int b = grow >> 10, t = grow & 1023;
        int hp = t >> 5, wpp = t & 31;
        int p = gcol / 3; int c = gcol - p * 3;
        int p1 = p >> 3, p2 = p & 7;
        out_f[(((size_t)(b * 3 + c) * 256 + hp * 8 + p1) * 256) + wpp * 8 + p2] = v;
      }
    }
  }
}

// ---------------- attention: in-block split-K flash, 32 q/block, 4 waves over keys ----------
union PW { u32 w[4]; bf16x8 v; };

__device__ __forceinline__ u32 pkbf(float a, float b) {
  union { bf16_t h[2]; u32 w; } u;
  u.h[0] = (bf16_t)a; u.h[1] = (bf16_t)b;
  return u.w;
}

__device__ __forceinline__ void pl32swap(u32& a, u32& b) {
  asm volatile("v_permlane32_swap_b32 %0, %1" : "+v"(a), "+v"(b));
}

#define SMEM_BYTES 32768

__device__ __forceinline__ void stage_kv(const bf16_t* kbase, const bf16_t* vbase,
                                         int ch, char* smem, int cur,
                                         int tid, int wid) {
  bf16_t* kl = (bf16_t*)(smem + cur * 8192);
  bf16_t* vl = (bf16_t*)(smem + 16384 + cur * 8192);
  #pragma unroll
  for (int s = 0; s < 2; s++) {
    int c = tid + s * 256;
    int row = c >> 2, cs = (c & 3) ^ (row & 3);
    gload_lds16(kbase + (size_t)(ch * 128 + row) * 32 + cs * 8,
                kl + (size_t)(s * 256 + wid * 64) * 8);
  }
  #pragma unroll
  for (int s = 0; s < 2; s++) {
    int c = tid + s * 256;
    int row = c >> 4, cs = (c & 15) ^ (row & 15);
    gload_lds16(vbase + (size_t)row * 1024 + ch * 128 + cs * 8,
                vl + (size_t)(s * 256 + wid * 64) * 8);
  }
}

__global__ __launch_bounds__(256, 4)
void attn_kernel(const bf16_t* __restrict__ q, const bf16_t* __restrict__ k,
                 const bf16_t* __restrict__ vt, const float* __restrict__ bias,
                 bf16_t* __restrict__ out) {
  __shared__ __align__(16) char smem[SMEM_BYTES];

  int tid = threadIdx.x, lane = tid & 63, wid = tid >> 6;
  int l31 = lane & 31, g = lane >> 5;
  int x = blockIdx.x & 7, idx = blockIdx.x >> 3;
  int qt = idx & 31;
  int bh = ((idx >> 5) << 3) | x;
  int b = bh >> 3, h = bh & 7;
  int q0 = qt * 32;
  const bf16_t* qp = q + ((size_t)bh * 1024 + q0 + l31) * 32;
  bf16x8 qf0 = *(const bf16x8*)(qp + g * 8);
  bf16x8 qf1 = *(const bf16x8*)(qp + 16 + g * 8);
  const bf16_t* kbase = k + (size_t)bh * 32768;
  const bf16_t* vbase = vt + (size_t)bh * 32768;
  const float* bb = bias + b * 1024;

  f32x16 acc;
  #pragma unroll
  for (int r = 0; r < 16; r++) acc[r] = 0.f;
  float lsum = 0.f;

  stage_kv(kbase, vbase, 0, smem, 0, tid, wid);
  __syncthreads();

  int cur = 0;
  for (int ch = 0; ch < 8; ch++) {
    if (ch < 7) stage_kv(kbase, vbase, ch + 1, smem, cur ^ 1, tid, wid);
    const bf16_t* kl = (const bf16_t*)(smem + cur * 8192);
    const bf16_t* vl = (const bf16_t*)(smem + 16384 + cur * 8192);
    int base = ch * 128 + wid * 32;
    int row0 = wid * 32 + l31;
    bf16x8 kA = *(const bf16x8*)(kl + (size_t)(row0 * 4 + (g ^ (row0 & 3))) * 8);
    bf16x8 kB = *(const bf16x8*)(kl + (size_t)(row0 * 4 + ((2 + g) ^ (row0 & 3))) * 8);
    bf16x8 vA = *(const bf16x8*)(vl + (size_t)(l31 * 16 + ((wid * 4 + g) ^ (l31 & 15))) * 8);
    bf16x8 vB = *(const bf16x8*)(vl + (size_t)(l31 * 16 + ((wid * 4 + 2 + g) ^ (l31 & 15))) * 8);
    f32x4 c0 = *(const f32x4*)(bb + base + 4 * g);
    f32x4 c1 = *(const f32x4*)(bb + base + 8 + 4 * g);
    f32x4 c2 = *(const f32x4*)(bb + base + 16 + 4 * g);
    f32x4 c3 = *(const f32x4*)(bb + base + 24 + 4 * g);
    f32x16 S;
    S[0] = c0[0]; S[1] = c0[1]; S[2] = c0[2]; S[3] = c0[3];
    S[4] = c1[0]; S[5] = c1[1]; S[6] = c1[2]; S[7] = c1[3];
    S[8] = c2[0]; S[9] = c2[1]; S[10] = c2[2]; S[11] = c2[3];
    S[12] = c3[0]; S[13] = c3[1]; S[14] = c3[2]; S[15] = c3[3];
    S = mfma32(kA, qf0, S);            // S^T[key][q], log2 domain, bias as C
    S = mfma32(kB, qf1, S);
    float p[16];
    #pragma unroll
    for (int r = 0; r < 16; r++) p[r] = exp2f(S[r]);
    lsum += (((p[0] + p[1]) + (p[2] + p[3])) + ((p[4] + p[5]) + (p[6] + p[7]))) +
            (((p[8] + p[9]) + (p[10] + p[11])) + ((p[12] + p[13]) + (p[14] + p[15])));
    u32 w[8];
    #pragma unroll
    for (int j = 0; j < 8; j++) w[j] = pkbf(p[2 * j], p[2 * j + 1]);
    u32 xa = w[2], ya = w[0]; pl32swap(xa, ya);
    u32 xb = w[3], yb = w[1]; pl32swap(xb, yb);
    u32 xc = w[6], yc = w[4]; pl32swap(xc, yc);
    u32 xd = w[7], yd = w[5]; pl32swap(xd, yd);
    PW A0, A1;
    A0.w[0] = g ? xa : w[0];  A0.w[2] = g ? w[2] : ya;
    A0.w[1] = g ? xb : w[1];  A0.w[3] = g ? w[3] : yb;
    A1.w[0] = g ? xc : w[4];  A1.w[2] = g ? w[6] : yc;
    A1.w[1] = g ? xd : w[5];  A1.w[3] = g ? w[7] : yd;
    acc = mfma32(A0.v, vA, acc);
    acc = mfma32(A1.v, vB, acc);
    __syncthreads();
    cur ^= 1;
  }

  float* OL = (float*)smem;                  // [4][32][33]
  float* LS = (float*)(smem + 16896);        // [4][32]
  #pragma unroll
  for (int r = 0; r < 16; r++) {
    int row = (r & 3) + 8 * (r >> 2) + 4 * g;
    OL[wid * 1056 + row * 33 + l31] = acc[r];
  }
  lsum += __shfl_xor(lsum, 32);
  LS[wid * 32 + l31] = lsum;
  __syncthreads();

  int qq = tid >> 3, d0 = (tid & 7) * 4;
  float l = LS[qq] + LS[32 + qq] + LS[64 + qq] + LS[96 + qq];
  float o0 = 0.f, o1 = 0.f, o2 = 0.f, o3 = 0.f;
  #pragma unroll
  for (int w2 = 0; w2 < 4; w2++) {
    const float* p = &OL[w2 * 1056 + qq * 33 + d0];
    o0 += p[0]; o1 += p[1]; o2 += p[2]; o3 += p[3];
  }
  float linv = 1.f / l;
  bf16x4 ov;
  ov[0] = (bf16_t)(o0 * linv); ov[1] = (bf16_t)(o1 * linv);
  ov[2] = (bf16_t)(o2 * linv); ov[3] = (bf16_t)(o3 * linv);
  *(bf16x4*)(out + ((size_t)b * 1024 + q0 + qq) * 256 + h * 32 + d0) = ov;
}

// ---------------- launch ----------------
extern "C" void kernel_launch(void* const* d_in, const int* in_sizes, int n_in,
                              void* d_out, int out_size, void* d_ws, size_t ws_size,
                              hipStream_t stream) {
  (void)in_sizes; (void)n_in; (void)out_size; (void)ws_size;
  const float* img0    = (const float*)d_in[0];
  const float* img1    = (const float*)d_in[1];
  const float* mask    = (const float*)d_in[2];
  const float* w_patch = (const float*)d_in[3];
  const float* b_patch = (const float*)d_in[4];
  const float* w_kv    = (const float*)d_in[5];
  const float* b_kv    = (const float*)d_in[6];
  const float* w_qv    = (const float*)d_in[7];
  const float* b_qv    = (const float*)d_in[8];
  const float* w_fc1   = (const float*)d_in[9];
  const float* b_fc1   = (const float*)d_in[10];
  const float* w_fc2   = (const float*)d_in[11];
  const float* b_fc2   = (const float*)d_in[12];
  float* out = (float*)d_out;

  char* ws = (char*)d_ws;
  float*  pe    = (float*)(ws + 0);
  float*  bias  = (float*)(ws + 1048576);
  bf16_t* wpT   = (bf16_t*)(ws + 1081344);
  bf16_t* wkvT  = (bf16_t*)(ws + 1179648);
  bf16_t* wqT   = (bf16_t*)(ws + 1441792);
  bf16_t* wfc1T = (bf16_t*)(ws + 1572864);
  bf16_t* wfc2T = (bf16_t*)(ws + 2097152);
  bf16_t* xp0   = (bf16_t*)(ws + 2621440);
  bf16_t* xp1   = (bf16_t*)(ws + 5767168);
  bf16_t* x0    = (bf16_t*)(ws + 8912896);
  bf16_t* x1    = (bf16_t*)(ws + 13107200);
  bf16_t* kbuf  = (bf16_t*)(ws + 17301504);
  bf16_t* vtbuf = (bf16_t*)(ws + 21495808);
  bf16_t* qbuf  = (bf16_t*)(ws + 25690112);
  bf16_t* aout  = (bf16_t*)(ws + 29884416);
  bf16_t* hbuf  = (bf16_t*)(ws + 34078720);

  prep_all<<<2772, 256, 0, stream>>>(img0, img1, mask, w_patch, w_kv, w_qv, w_fc1, w_fc2,
                                     xp0, xp1, pe, bias, wpT, wkvT, wqT, wfc1T, wfc2T);

  gemm128d<0, 64><<<dim3(64, 4, 2), 256, 0, stream>>>(xp0, xp1, wpT, nullptr, 8192, 256, 192,
                                                      b_patch, nullptr, pe, x0, x1, nullptr, nullptr);
  gemm128d<5, 128><<<dim3(64, 6), 256, 0, stream>>>(x0, x1, wkvT, wqT, 8192, 512, 256,
                                                    b_kv, b_qv, nullptr, kbuf, vtbuf, qbuf, nullptr);

  attn_kernel<<<2048, 256, 0, stream>>>(qbuf, kbuf, vtbuf, bias, aout);

  gemm128d<3, 128><<<dim3(64, 8), 256, 0, stream>>>(aout, nullptr, wfc1T, nullptr, 8192, 1024, 256,
                                                    b_fc1, nullptr, nullptr, hbuf, nullptr, nullptr, nullptr);
  gemm_fc2<64><<<dim3(128, 3), 256, 0, stream>>>(hbuf, wfc2T, 8192, 256, 1024, b_fc2, out);
}